// Round 5
// baseline (266.255 us; speedup 1.0000x reference)
//
#include <hip/hip_runtime.h>

#define NQ 1024
#define NK 1024
#define DD 512
#define HH 8
#define DH 64
#define BB 4
#define EPS 1e-5f

typedef short bf16x8 __attribute__((ext_vector_type(8)));
typedef short short4v __attribute__((ext_vector_type(4)));
typedef short short2v __attribute__((ext_vector_type(2)));
typedef float f32x4 __attribute__((ext_vector_type(4)));

__device__ __forceinline__ unsigned short f2bf(float f) {
    union { float f; unsigned u; } v; v.f = f;
    unsigned r = v.u + 0x7FFFu + ((v.u >> 16) & 1u);
    return (unsigned short)(r >> 16);
}

// raw v_exp_f32 (2^x); args bounded |x|<~10 here, no denorm/overflow concerns
__device__ __forceinline__ float fexp2(float x) { return __builtin_amdgcn_exp2f(x); }

// async 16B global -> LDS (dest linear: wave-uniform base + lane*16)
__device__ __forceinline__ void gld_lds16(const short* g, short* l) {
    __builtin_amdgcn_global_load_lds(
        (const __attribute__((address_space(1))) unsigned int*)g,
        (__attribute__((address_space(3))) unsigned int*)l, 16, 0, 0);
}

// XOR swizzle on 16B-block index within a 128B row (involution; applied to
// global SOURCE at stage time and to ds_read address at use time)
#define SWZ(blk, r) ((blk) ^ ((r) & 7))

// ---- transpose-convert 4 weights W[k][n] fp32 -> WT[n][k] bf16 ----
__global__ __launch_bounds__(256) void wconv(const float* __restrict__ W0, const float* __restrict__ W1,
                                             const float* __restrict__ W2, const float* __restrict__ W3,
                                             short* __restrict__ WT)
{
    __shared__ float tile[32][33];
    const float* Wsel = (blockIdx.z == 0) ? W0 : (blockIdx.z == 1) ? W1 : (blockIdx.z == 2) ? W2 : W3;
    short* T = WT + (size_t)blockIdx.z * DD * DD;
    const int n0 = blockIdx.x * 32, k0 = blockIdx.y * 32;
    const int tx = threadIdx.x & 31, ty = threadIdx.x >> 5;
    #pragma unroll
    for (int p = 0; p < 4; ++p)
        tile[ty + p * 8][tx] = Wsel[(size_t)(k0 + ty + p * 8) * DD + n0 + tx];
    __syncthreads();
    #pragma unroll
    for (int p = 0; p < 4; ++p)
        T[(size_t)(n0 + ty + p * 8) * DD + k0 + tx] = (short)f2bf(tile[tx][ty + p * 8]);
}

// ---- fp32 -> bf16 bulk convert: qx then kx, 8 elems/thread ----
__global__ __launch_bounds__(256) void cvt_bf16(const float* __restrict__ qx,
                                                const float* __restrict__ kx,
                                                short* __restrict__ qxb,
                                                short* __restrict__ kxb)
{
    const int half = (BB * NQ * DD) / 8;           // 262144
    int i = blockIdx.x * 256 + threadIdx.x;
    const float* X = (i < half) ? qx : kx;
    short* Y = (i < half) ? qxb : kxb;
    int j = (i < half) ? i : i - half;
    float4 v0 = ((const float4*)X)[(size_t)j * 2];
    float4 v1 = ((const float4*)X)[(size_t)j * 2 + 1];
    bf16x8 o;
    o[0] = f2bf(v0.x); o[1] = f2bf(v0.y); o[2] = f2bf(v0.z); o[3] = f2bf(v0.w);
    o[4] = f2bf(v1.x); o[5] = f2bf(v1.y); o[6] = f2bf(v1.z); o[7] = f2bf(v1.w);
    ((bf16x8*)Y)[j] = o;
}

// ---- MFMA GEMM, m97-style: 128x64 tile, BK=64, global_load_lds + XOR swizzle.
template<int MODE>
__global__ __launch_bounds__(256) void gemm128(const short* __restrict__ Aq,
                                               const short* __restrict__ Akv,
                                               const short* __restrict__ BT,
                                               const float* __restrict__ b0,
                                               const float* __restrict__ b1,
                                               const float* __restrict__ b2,
                                               void* __restrict__ O0,
                                               void* __restrict__ O1,
                                               void* __restrict__ O2)
{
    __shared__ __align__(16) short sbuf[128 * 64 + 64 * 64];
    short* As = sbuf;
    short* Bs = sbuf + 128 * 64;

    const int t = threadIdx.x;
    const int m0 = blockIdx.y * 128;
    const int nB0 = blockIdx.x * 64;

    const short* A;
    const float* bias;
    void* Op;
    int n0;
    if (MODE == 0) {
        const int idx = nB0 >> 9;
        n0 = nB0 & 511;
        A    = (idx == 0) ? Aq : Akv;
        bias = (idx == 0) ? b0 : (idx == 1) ? b1 : b2;
        Op   = (idx == 0) ? O0 : (idx == 1) ? O1 : O2;
    } else {
        A = Aq; bias = b0; Op = O0; n0 = nB0;
    }

    const int lane = t & 63, wv = t >> 6;
    const int quad = lane >> 4, mrow = lane & 15;
    const int wm = wv >> 1, wn = wv & 1;

    const int ar = t >> 3;
    const int aj = t & 7;

    f32x4 acc[4][2] = {};

    for (int k0 = 0; k0 < DD; k0 += 64) {
        #pragma unroll
        for (int i = 0; i < 4; ++i) {
            int r = i * 32 + ar;
            int jg = SWZ(aj, r);
            gld_lds16(A + (size_t)(m0 + r) * DD + k0 + jg * 8, As + (size_t)(i * 256 + t) * 8);
        }
        #pragma unroll
        for (int i = 0; i < 2; ++i) {
            int r = i * 32 + ar;
            int jg = SWZ(aj, r);
            gld_lds16(BT + (size_t)(nB0 + r) * DD + k0 + jg * 8, Bs + (size_t)(i * 256 + t) * 8);
        }
        __syncthreads();

        #pragma unroll
        for (int ks = 0; ks < 2; ++ks) {
            const int blk = SWZ(ks * 4 + quad, mrow);
            bf16x8 bfr[2];
            #pragma unroll
            for (int n = 0; n < 2; ++n) {
                int row = wn * 32 + n * 16 + mrow;
                bfr[n] = *(const bf16x8*)(Bs + row * 64 + blk * 8);
            }
            #pragma unroll
            for (int m = 0; m < 4; ++m) {
                int row = wm * 64 + m * 16 + mrow;
                bf16x8 afr = *(const bf16x8*)(As + row * 64 + blk * 8);
                acc[m][0] = __builtin_amdgcn_mfma_f32_16x16x32_bf16(afr, bfr[0], acc[m][0], 0, 0, 0);
                acc[m][1] = __builtin_amdgcn_mfma_f32_16x16x32_bf16(afr, bfr[1], acc[m][1], 0, 0, 0);
            }
        }
        __syncthreads();
    }

    if (MODE == 0) {
        short* Es = sbuf;
        #pragma unroll
        for (int m = 0; m < 4; ++m) {
            #pragma unroll
            for (int n = 0; n < 2; ++n) {
                int col = wn * 32 + n * 16 + mrow;
                float bv_ = bias[n0 + col];
                #pragma unroll
                for (int r = 0; r < 4; ++r) {
                    int row = wm * 64 + m * 16 + quad * 4 + r;
                    Es[row * 72 + col] = (short)f2bf(acc[m][n][r] + bv_);
                }
            }
        }
        __syncthreads();
        short* Ob = (short*)Op;
        #pragma unroll
        for (int i = 0; i < 4; ++i) {
            int r = i * 32 + ar;
            *(bf16x8*)(Ob + (size_t)(m0 + r) * DD + n0 + aj * 8) = *(const bf16x8*)(Es + r * 72 + aj * 8);
        }
    } else {
        float* Of = (float*)Op;
        #pragma unroll
        for (int m = 0; m < 4; ++m) {
            #pragma unroll
            for (int n = 0; n < 2; ++n) {
                int col = n0 + wn * 32 + n * 16 + mrow;
                float bv_ = bias[col];
                #pragma unroll
                for (int r = 0; r < 4; ++r) {
                    int row = m0 + wm * 64 + m * 16 + quad * 4 + r;
                    Of[(size_t)row * DD + col] = acc[m][n][r] + bv_;
                }
            }
        }
    }
}

// ---- fused attention v3: no-max softmax (p=exp2(v) bounded), K direct from
// global (no LDS staging), pass A = QK+exp+l+PV (1 barrier/tile), pass B = w
// stream (0 barriers). LDS 31.7 KB -> 5 blocks/CU. ----
__global__ __launch_bounds__(256) void attn_fused(const short* __restrict__ Qb,
                                                  const short* __restrict__ Kb,
                                                  const short* __restrict__ Vb,
                                                  const float* __restrict__ logg,
                                                  float* __restrict__ wout,
                                                  short* __restrict__ ctx)
{
    __shared__ __align__(16) short VTs[2][64 * 72];   // transposed V, padded, dbuf
    __shared__ __align__(16) short Ps[64 * 72];       // wave-private rows
    __shared__ float lg[NK];

    const int t = threadIdx.x;
    // XCD-chunked swizzle: 512 blocks, 8 XCDs -> 64 consecutive per XCD
    const int bid = (int)blockIdx.x;
    const int nb = (bid & 7) * 64 + (bid >> 3);
    const int bh = nb >> 4;
    const int q0 = (nb & 15) << 6;
    const int b = bh >> 3, h = bh & 7;
    const int lane = t & 63, wv = t >> 6;
    const int quad = lane >> 4, mrow = lane & 15;

    const float C2 = 0.18033688011112042f;   // 0.125 * log2(e)
    const float L2E = 1.4426950408889634f;

    #pragma unroll
    for (int i = 0; i < 4; ++i) lg[t + i * 256] = logg[b * NK + t + i * 256] * L2E;

    // Q fragments direct from global (read once)
    const short* Qp = Qb + (size_t)(b * NQ + q0 + wv * 16 + mrow) * DD + h * DH;
    bf16x8 qa0 = *(const bf16x8*)(Qp + quad * 8);
    bf16x8 qa1 = *(const bf16x8*)(Qp + 32 + quad * 8);

    const short* Kbase = Kb + (size_t)(b * NK) * DD + h * DH;

    const int kp = t & 31, dblk = t >> 5;
    const short* Vbase = Vb + (size_t)(b * NK) * DD + h * DH + dblk * 8;

    // prologue: V(0) load + pack VTs[0]; V(1) load into regs
    bf16x8 v0r, v1r;
    {
        const short* p = Vbase + (size_t)(2 * kp) * DD;
        v0r = *(const bf16x8*)p;
        v1r = *(const bf16x8*)(p + DD);
        #pragma unroll
        for (int jj = 0; jj < 8; ++jj) {
            short2v pr; pr[0] = v0r[jj]; pr[1] = v1r[jj];
            *(short2v*)&VTs[0][(dblk * 8 + jj) * 72 + 2 * kp] = pr;
        }
        const short* p1 = Vbase + (size_t)(64 + 2 * kp) * DD;
        v0r = *(const bf16x8*)p1;
        v1r = *(const bf16x8*)(p1 + DD);
    }
    __syncthreads();   // covers lg + VTs[0]

    float lloc[4] = {0.f, 0.f, 0.f, 0.f};
    f32x4 o[4] = {};

    // ---- pass A: QK^T (K direct), p=exp2(v), l accumulate, Ps, PV ----
    for (int kt = 0; kt < 16; ++kt) {
        const int cur = kt & 1;
        // pack V(kt+1) (regs from last iter) into VTs[cur^1]; issue V(kt+2) loads
        if (kt < 15) {
            #pragma unroll
            for (int jj = 0; jj < 8; ++jj) {
                short2v pr; pr[0] = v0r[jj]; pr[1] = v1r[jj];
                *(short2v*)&VTs[cur ^ 1][(dblk * 8 + jj) * 72 + 2 * kp] = pr;
            }
            if (kt < 14) {
                const short* p = Vbase + (size_t)((kt + 2) * 64 + 2 * kp) * DD;
                v0r = *(const bf16x8*)p;
                v1r = *(const bf16x8*)(p + DD);
            }
        }
        const int k0 = kt * 64;
        f32x4 sj[4];
        __builtin_amdgcn_s_setprio(1);
        #pragma unroll
        for (int j = 0; j < 4; ++j) {
            const short* kr = Kbase + (size_t)(k0 + j * 16 + mrow) * DD;
            bf16x8 kb0 = *(const bf16x8*)(kr + quad * 8);
            bf16x8 kb1 = *(const bf16x8*)(kr + 32 + quad * 8);
            f32x4 z = {0.f, 0.f, 0.f, 0.f};
            z = __builtin_amdgcn_mfma_f32_16x16x32_bf16(qa0, kb0, z, 0, 0, 0);
            z = __builtin_amdgcn_mfma_f32_16x16x32_bf16(qa1, kb1, z, 0, 0, 0);
            sj[j] = z;
        }
        __builtin_amdgcn_s_setprio(0);
        #pragma unroll
        for (int j = 0; j < 4; ++j) {
            float lgv = lg[k0 + j * 16 + mrow];
            #pragma unroll
            for (int r = 0; r < 4; ++r) {
                float p = fexp2(fmaf(sj[j][r], C2, lgv));
                lloc[r] += p;
                Ps[(wv * 16 + quad * 4 + r) * 72 + j * 16 + mrow] = (short)f2bf(p);
            }
        }
        __builtin_amdgcn_s_setprio(1);
        #pragma unroll
        for (int ks = 0; ks < 2; ++ks) {
            bf16x8 pa = *(const bf16x8*)&Ps[(wv * 16 + mrow) * 72 + ks * 32 + quad * 8];
            #pragma unroll
            for (int jp = 0; jp < 4; ++jp) {
                bf16x8 vb = *(const bf16x8*)&VTs[cur][(jp * 16 + mrow) * 72 + ks * 32 + quad * 8];
                o[jp] = __builtin_amdgcn_mfma_f32_16x16x32_bf16(pa, vb, o[jp], 0, 0, 0);
            }
        }
        __builtin_amdgcn_s_setprio(0);
        __syncthreads();
    }

    // ---- combine l across the 16 mrow lanes (pure adds) ----
    float invl[4];
    #pragma unroll
    for (int r = 0; r < 4; ++r) {
        float l = lloc[r];
        #pragma unroll
        for (int off = 1; off < 16; off <<= 1) l += __shfl_xor(l, off);
        invl[r] = 1.f / l;
    }

    // ---- ctx write (scale by invl) ----
    #pragma unroll
    for (int jp = 0; jp < 4; ++jp)
        #pragma unroll
        for (int r = 0; r < 4; ++r)
            ctx[(size_t)(b * NQ + q0 + wv * 16 + quad * 4 + r) * DD + h * DH + jp * 16 + mrow] =
                (short)f2bf(o[jp][r] * invl[r]);

    // ---- pass B: w stream — K direct, no LDS (except lg), no barriers ----
    for (int kt = 0; kt < 16; ++kt) {
        const int k0 = kt * 64;
        f32x4 sj[4];
        #pragma unroll
        for (int j = 0; j < 4; ++j) {
            const short* kr = Kbase + (size_t)(k0 + j * 16 + mrow) * DD;
            bf16x8 kb0 = *(const bf16x8*)(kr + quad * 8);
            bf16x8 kb1 = *(const bf16x8*)(kr + 32 + quad * 8);
            f32x4 z = {0.f, 0.f, 0.f, 0.f};
            z = __builtin_amdgcn_mfma_f32_16x16x32_bf16(qa0, kb0, z, 0, 0, 0);
            z = __builtin_amdgcn_mfma_f32_16x16x32_bf16(qa1, kb1, z, 0, 0, 0);
            sj[j] = z;
        }
        #pragma unroll
        for (int j = 0; j < 4; ++j) {
            float lgv = lg[k0 + j * 16 + mrow];
            #pragma unroll
            for (int r = 0; r < 4; ++r) {
                wout[((size_t)bh * NQ + q0 + wv * 16 + quad * 4 + r) * NK + k0 + j * 16 + mrow] =
                    fexp2(fmaf(sj[j][r], C2, lgv)) * invl[r];
            }
        }
    }
}

// ---- Residual + LayerNorm ----
__global__ __launch_bounds__(256) void add_ln(const float* __restrict__ X,
                                              const float* __restrict__ qx,
                                              const float* __restrict__ g,
                                              const float* __restrict__ bb,
                                              float* __restrict__ out)
{
    __shared__ float red[16];
    const int row = blockIdx.x;
    const int t = threadIdx.x;
    const float* xr = X + (size_t)row * DD;
    const float* qr = qx + (size_t)row * DD;
    float v0 = xr[t] + qr[t];
    float v1 = xr[t + 256] + qr[t + 256];
    float sum = v0 + v1;
    float sq = v0 * v0 + v1 * v1;
    #pragma unroll
    for (int off = 32; off > 0; off >>= 1) {
        sum += __shfl_down(sum, off);
        sq += __shfl_down(sq, off);
    }
    const int wid = t >> 6, lane = t & 63;
    if (lane == 0) { red[wid] = sum; red[8 + wid] = sq; }
    __syncthreads();
    if (t == 0) {
        float s = red[0] + red[1] + red[2] + red[3];
        float q2 = red[8] + red[9] + red[10] + red[11];
        float mu = s / (float)DD;
        float var = q2 / (float)DD - mu * mu;
        red[4] = mu;
        red[5] = rsqrtf(var + EPS);
    }
    __syncthreads();
    const float mu = red[4], inv = red[5];
    out[(size_t)row * DD + t] = (v0 - mu) * inv * g[t] + bb[t];
    out[(size_t)row * DD + t + 256] = (v1 - mu) * inv * g[t + 256] + bb[t + 256];
}

extern "C" void kernel_launch(void* const* d_in, const int* in_sizes, int n_in,
                              void* d_out, int out_size, void* d_ws, size_t ws_size,
                              hipStream_t stream) {
    const float* qx   = (const float*)d_in[0];
    const float* kx   = (const float*)d_in[1];
    const float* logg = (const float*)d_in[4];
    const float* Wq   = (const float*)d_in[5];
    const float* bq   = (const float*)d_in[6];
    const float* Wk   = (const float*)d_in[7];
    const float* bk   = (const float*)d_in[8];
    const float* Wv   = (const float*)d_in[9];
    const float* bv   = (const float*)d_in[10];
    const float* Wo   = (const float*)d_in[11];
    const float* bo   = (const float*)d_in[12];
    const float* ln_g = (const float*)d_in[13];
    const float* ln_b = (const float*)d_in[14];

    float* out0  = (float*)d_out;
    float* w_out = out0 + (size_t)BB * NQ * DD;

    const size_t rows = (size_t)BB * NQ;          // 4096
    short* WT  = (short*)d_ws;                    // 4 x 512 x 512 bf16 (2 MB)
    short* qxb = WT + (size_t)4 * DD * DD;
    short* kxb = qxb + rows * DD;
    short* Qb  = kxb + rows * DD;
    short* Kb  = Qb + rows * DD;
    short* Vb  = Kb + rows * DD;
    short* Cxb = Vb + rows * DD;
    float* Xb  = (float*)(Cxb + rows * DD);

    wconv<<<dim3(DD / 32, DD / 32, 4), 256, 0, stream>>>(Wq, Wk, Wv, Wo, WT);
    cvt_bf16<<<2048, 256, 0, stream>>>(qx, kx, qxb, kxb);

    gemm128<0><<<dim3(1536 / 64, (int)(rows / 128)), 256, 0, stream>>>(
        qxb, kxb, WT, bq, bk, bv, Qb, Kb, Vb);

    attn_fused<<<dim3(512), 256, 0, stream>>>(Qb, Kb, Vb, logg, w_out, Cxb);

    gemm128<1><<<dim3(DD / 64, (int)(rows / 128)), 256, 0, stream>>>(
        Cxb, nullptr, WT + 3 * DD * DD, bo, nullptr, nullptr, Xb, nullptr, nullptr);

    add_ln<<<(int)rows, 256, 0, stream>>>(Xb, qx, ln_g, ln_b, out0);
}

// Round 6
// 232.991 us; speedup vs baseline: 1.1428x; 1.1428x over previous
//
#include <hip/hip_runtime.h>

#define NQ 1024
#define NK 1024
#define DD 512
#define HH 8
#define DH 64
#define BB 4
#define EPS 1e-5f

typedef short bf16x8 __attribute__((ext_vector_type(8)));
typedef short short4v __attribute__((ext_vector_type(4)));
typedef short short2v __attribute__((ext_vector_type(2)));
typedef float f32x4 __attribute__((ext_vector_type(4)));

__device__ __forceinline__ unsigned short f2bf(float f) {
    union { float f; unsigned u; } v; v.f = f;
    unsigned r = v.u + 0x7FFFu + ((v.u >> 16) & 1u);
    return (unsigned short)(r >> 16);
}

// raw v_exp_f32 (2^x); args bounded |x|<~14 here, no denorm/overflow concerns
__device__ __forceinline__ float fexp2(float x) { return __builtin_amdgcn_exp2f(x); }

// async 16B global -> LDS (dest linear: wave-uniform base + lane*16)
__device__ __forceinline__ void gld_lds16(const short* g, short* l) {
    __builtin_amdgcn_global_load_lds(
        (const __attribute__((address_space(1))) unsigned int*)g,
        (__attribute__((address_space(3))) unsigned int*)l, 16, 0, 0);
}

// XOR swizzle on 16B-block index within a 128B row (involution; applied to
// global SOURCE at stage time and to ds_read address at use time)
#define SWZ(blk, r) ((blk) ^ ((r) & 7))

// ---- transpose-convert 4 weights W[k][n] fp32 -> WT[n][k] bf16 ----
__global__ __launch_bounds__(256) void wconv(const float* __restrict__ W0, const float* __restrict__ W1,
                                             const float* __restrict__ W2, const float* __restrict__ W3,
                                             short* __restrict__ WT)
{
    __shared__ float tile[32][33];
    const float* Wsel = (blockIdx.z == 0) ? W0 : (blockIdx.z == 1) ? W1 : (blockIdx.z == 2) ? W2 : W3;
    short* T = WT + (size_t)blockIdx.z * DD * DD;
    const int n0 = blockIdx.x * 32, k0 = blockIdx.y * 32;
    const int tx = threadIdx.x & 31, ty = threadIdx.x >> 5;
    #pragma unroll
    for (int p = 0; p < 4; ++p)
        tile[ty + p * 8][tx] = Wsel[(size_t)(k0 + ty + p * 8) * DD + n0 + tx];
    __syncthreads();
    #pragma unroll
    for (int p = 0; p < 4; ++p)
        T[(size_t)(n0 + ty + p * 8) * DD + k0 + tx] = (short)f2bf(tile[tx][ty + p * 8]);
}

// ---- fp32 -> bf16 bulk convert: qx then kx, 8 elems/thread ----
__global__ __launch_bounds__(256) void cvt_bf16(const float* __restrict__ qx,
                                                const float* __restrict__ kx,
                                                short* __restrict__ qxb,
                                                short* __restrict__ kxb)
{
    const int half = (BB * NQ * DD) / 8;           // 262144
    int i = blockIdx.x * 256 + threadIdx.x;
    const float* X = (i < half) ? qx : kx;
    short* Y = (i < half) ? qxb : kxb;
    int j = (i < half) ? i : i - half;
    float4 v0 = ((const float4*)X)[(size_t)j * 2];
    float4 v1 = ((const float4*)X)[(size_t)j * 2 + 1];
    bf16x8 o;
    o[0] = f2bf(v0.x); o[1] = f2bf(v0.y); o[2] = f2bf(v0.z); o[3] = f2bf(v0.w);
    o[4] = f2bf(v1.x); o[5] = f2bf(v1.y); o[6] = f2bf(v1.z); o[7] = f2bf(v1.w);
    ((bf16x8*)Y)[j] = o;
}

// ---- MFMA GEMM, m97-style: 128x64 tile, BK=64, global_load_lds + XOR swizzle.
template<int MODE>
__global__ __launch_bounds__(256) void gemm128(const short* __restrict__ Aq,
                                               const short* __restrict__ Akv,
                                               const short* __restrict__ BT,
                                               const float* __restrict__ b0,
                                               const float* __restrict__ b1,
                                               const float* __restrict__ b2,
                                               void* __restrict__ O0,
                                               void* __restrict__ O1,
                                               void* __restrict__ O2)
{
    __shared__ __align__(16) short sbuf[128 * 64 + 64 * 64];
    short* As = sbuf;
    short* Bs = sbuf + 128 * 64;

    const int t = threadIdx.x;
    const int m0 = blockIdx.y * 128;
    const int nB0 = blockIdx.x * 64;

    const short* A;
    const float* bias;
    void* Op;
    int n0;
    if (MODE == 0) {
        const int idx = nB0 >> 9;
        n0 = nB0 & 511;
        A    = (idx == 0) ? Aq : Akv;
        bias = (idx == 0) ? b0 : (idx == 1) ? b1 : b2;
        Op   = (idx == 0) ? O0 : (idx == 1) ? O1 : O2;
    } else {
        A = Aq; bias = b0; Op = O0; n0 = nB0;
    }

    const int lane = t & 63, wv = t >> 6;
    const int quad = lane >> 4, mrow = lane & 15;
    const int wm = wv >> 1, wn = wv & 1;

    const int ar = t >> 3;
    const int aj = t & 7;

    f32x4 acc[4][2] = {};

    for (int k0 = 0; k0 < DD; k0 += 64) {
        #pragma unroll
        for (int i = 0; i < 4; ++i) {
            int r = i * 32 + ar;
            int jg = SWZ(aj, r);
            gld_lds16(A + (size_t)(m0 + r) * DD + k0 + jg * 8, As + (size_t)(i * 256 + t) * 8);
        }
        #pragma unroll
        for (int i = 0; i < 2; ++i) {
            int r = i * 32 + ar;
            int jg = SWZ(aj, r);
            gld_lds16(BT + (size_t)(nB0 + r) * DD + k0 + jg * 8, Bs + (size_t)(i * 256 + t) * 8);
        }
        __syncthreads();

        #pragma unroll
        for (int ks = 0; ks < 2; ++ks) {
            const int blk = SWZ(ks * 4 + quad, mrow);
            bf16x8 bfr[2];
            #pragma unroll
            for (int n = 0; n < 2; ++n) {
                int row = wn * 32 + n * 16 + mrow;
                bfr[n] = *(const bf16x8*)(Bs + row * 64 + blk * 8);
            }
            #pragma unroll
            for (int m = 0; m < 4; ++m) {
                int row = wm * 64 + m * 16 + mrow;
                bf16x8 afr = *(const bf16x8*)(As + row * 64 + blk * 8);
                acc[m][0] = __builtin_amdgcn_mfma_f32_16x16x32_bf16(afr, bfr[0], acc[m][0], 0, 0, 0);
                acc[m][1] = __builtin_amdgcn_mfma_f32_16x16x32_bf16(afr, bfr[1], acc[m][1], 0, 0, 0);
            }
        }
        __syncthreads();
    }

    if (MODE == 0) {
        short* Es = sbuf;
        #pragma unroll
        for (int m = 0; m < 4; ++m) {
            #pragma unroll
            for (int n = 0; n < 2; ++n) {
                int col = wn * 32 + n * 16 + mrow;
                float bv_ = bias[n0 + col];
                #pragma unroll
                for (int r = 0; r < 4; ++r) {
                    int row = wm * 64 + m * 16 + quad * 4 + r;
                    Es[row * 72 + col] = (short)f2bf(acc[m][n][r] + bv_);
                }
            }
        }
        __syncthreads();
        short* Ob = (short*)Op;
        #pragma unroll
        for (int i = 0; i < 4; ++i) {
            int r = i * 32 + ar;
            *(bf16x8*)(Ob + (size_t)(m0 + r) * DD + n0 + aj * 8) = *(const bf16x8*)(Es + r * 72 + aj * 8);
        }
    } else {
        float* Of = (float*)Op;
        #pragma unroll
        for (int m = 0; m < 4; ++m) {
            #pragma unroll
            for (int n = 0; n < 2; ++n) {
                int col = n0 + wn * 32 + n * 16 + mrow;
                float bv_ = bias[col];
                #pragma unroll
                for (int r = 0; r < 4; ++r) {
                    int row = m0 + wm * 64 + m * 16 + quad * 4 + r;
                    Of[(size_t)row * DD + col] = acc[m][n][r] + bv_;
                }
            }
        }
    }
}

// ---- fused attention v4: R4's v2 body (K via gld_lds+swz dbuf, 1 barrier/tile)
// + no-max softmax (bounded args: p=exp2(v) safe in fp32) ----
__global__ __launch_bounds__(256) void attn_fused(const short* __restrict__ Qb,
                                                  const short* __restrict__ Kb,
                                                  const short* __restrict__ Vb,
                                                  const float* __restrict__ logg,
                                                  float* __restrict__ wout,
                                                  short* __restrict__ ctx)
{
    __shared__ __align__(16) short Ks2[2][64 * 64];   // linear, gld_lds dest
    __shared__ __align__(16) short VTs[2][64 * 72];   // transposed V, padded
    __shared__ __align__(16) short Ps[64 * 72];
    __shared__ float lg[NK];

    const int t = threadIdx.x;
    // XCD-chunked swizzle: 512 blocks, 8 XCDs -> 64 consecutive per XCD
    const int bid = (int)blockIdx.x;
    const int nb = (bid & 7) * 64 + (bid >> 3);
    const int bh = nb >> 4;
    const int q0 = (nb & 15) << 6;
    const int b = bh >> 3, h = bh & 7;
    const int lane = t & 63, wv = t >> 6;
    const int quad = lane >> 4, mrow = lane & 15;

    const float C2 = 0.18033688011112042f;   // 0.125 * log2(e)
    const float L2E = 1.4426950408889634f;

    #pragma unroll
    for (int i = 0; i < 4; ++i) lg[t + i * 256] = logg[b * NK + t + i * 256] * L2E;

    // ---- stage Q (linear+swz) into VTs[1] region; K tile 0 into Ks2[0] ----
    #pragma unroll
    for (int i = 0; i < 2; ++i) {
        int f = t + i * 256, r = f >> 3, bk = f & 7;
        gld_lds16(Qb + (size_t)(b * NQ + q0 + r) * DD + h * DH + SWZ(bk, r) * 8,
                  &VTs[1][(size_t)f * 8]);
    }
    #pragma unroll
    for (int i = 0; i < 2; ++i) {
        int f = t + i * 256, r = f >> 3, bk = f & 7;
        gld_lds16(Kb + (size_t)(b * NK + r) * DD + h * DH + SWZ(bk, r) * 8,
                  &Ks2[0][(size_t)f * 8]);
    }
    __syncthreads();

    const int qrow = wv * 16 + mrow;
    bf16x8 qa0 = *(const bf16x8*)&VTs[1][qrow * 64 + SWZ(quad, qrow) * 8];
    bf16x8 qa1 = *(const bf16x8*)&VTs[1][qrow * 64 + SWZ(quad + 4, qrow) * 8];

    float lloc[4] = {0.f, 0.f, 0.f, 0.f};

    // ---- pass 1: per-lane l accumulate only (no max tracking); 1 barrier/tile ----
    for (int kt = 0; kt < 16; ++kt) {
        const int cur = kt & 1;
        if (kt < 15) {
            const int k0n = (kt + 1) * 64;
            #pragma unroll
            for (int i = 0; i < 2; ++i) {
                int f = t + i * 256, r = f >> 3, bk = f & 7;
                gld_lds16(Kb + (size_t)(b * NK + k0n + r) * DD + h * DH + SWZ(bk, r) * 8,
                          &Ks2[cur ^ 1][(size_t)f * 8]);
            }
        }
        const int k0 = kt * 64;
        f32x4 sj[4];
        __builtin_amdgcn_s_setprio(1);
        #pragma unroll
        for (int j = 0; j < 4; ++j) {
            int row = j * 16 + mrow;
            bf16x8 kb0 = *(const bf16x8*)&Ks2[cur][row * 64 + SWZ(quad, row) * 8];
            bf16x8 kb1 = *(const bf16x8*)&Ks2[cur][row * 64 + SWZ(quad + 4, row) * 8];
            f32x4 z = {0.f, 0.f, 0.f, 0.f};
            z = __builtin_amdgcn_mfma_f32_16x16x32_bf16(qa0, kb0, z, 0, 0, 0);
            z = __builtin_amdgcn_mfma_f32_16x16x32_bf16(qa1, kb1, z, 0, 0, 0);
            sj[j] = z;
        }
        __builtin_amdgcn_s_setprio(0);
        float lg0 = lg[k0 + mrow],      lg1 = lg[k0 + 16 + mrow];
        float lg2 = lg[k0 + 32 + mrow], lg3 = lg[k0 + 48 + mrow];
        #pragma unroll
        for (int r = 0; r < 4; ++r) {
            lloc[r] += fexp2(fmaf(sj[0][r], C2, lg0)) + fexp2(fmaf(sj[1][r], C2, lg1))
                     + fexp2(fmaf(sj[2][r], C2, lg2)) + fexp2(fmaf(sj[3][r], C2, lg3));
        }
        __syncthreads();
    }

    // ---- combine l across the 16 mrow lanes (pure adds) ----
    float invl[4];
    #pragma unroll
    for (int r = 0; r < 4; ++r) {
        float l = lloc[r];
        #pragma unroll
        for (int off = 1; off < 16; off <<= 1) l += __shfl_xor(l, off);
        invl[r] = 1.f / l;
    }

    // ---- pass 2: recompute S, write w, PV; 1 barrier per tile ----
    const int kp = t & 31, dblk = t >> 5;
    bf16x8 v0r, v1r;
    f32x4 o[4] = {};

    // prologue: K0 restage, V0 load+pack, V1 load
    #pragma unroll
    for (int i = 0; i < 2; ++i) {
        int f = t + i * 256, r = f >> 3, bk = f & 7;
        gld_lds16(Kb + (size_t)(b * NK + r) * DD + h * DH + SWZ(bk, r) * 8,
                  &Ks2[0][(size_t)f * 8]);
    }
    {
        const short* p = Vb + (size_t)(b * NK + 2 * kp) * DD + h * DH + dblk * 8;
        v0r = *(const bf16x8*)p;
        v1r = *(const bf16x8*)(p + DD);
        #pragma unroll
        for (int jj = 0; jj < 8; ++jj) {
            short2v pr; pr[0] = v0r[jj]; pr[1] = v1r[jj];
            *(short2v*)&VTs[0][(dblk * 8 + jj) * 72 + 2 * kp] = pr;
        }
        const short* p1 = Vb + (size_t)(b * NK + 64 + 2 * kp) * DD + h * DH + dblk * 8;
        v0r = *(const bf16x8*)p1;
        v1r = *(const bf16x8*)(p1 + DD);
    }
    __syncthreads();

    for (int kt = 0; kt < 16; ++kt) {
        const int cur = kt & 1;
        if (kt < 15) {
            const int k0n = (kt + 1) * 64;
            #pragma unroll
            for (int i = 0; i < 2; ++i) {
                int f = t + i * 256, r = f >> 3, bk = f & 7;
                gld_lds16(Kb + (size_t)(b * NK + k0n + r) * DD + h * DH + SWZ(bk, r) * 8,
                          &Ks2[cur ^ 1][(size_t)f * 8]);
            }
        }
        const int k0 = kt * 64;
        f32x4 sj[4];
        __builtin_amdgcn_s_setprio(1);
        #pragma unroll
        for (int j = 0; j < 4; ++j) {
            int row = j * 16 + mrow;
            bf16x8 kb0 = *(const bf16x8*)&Ks2[cur][row * 64 + SWZ(quad, row) * 8];
            bf16x8 kb1 = *(const bf16x8*)&Ks2[cur][row * 64 + SWZ(quad + 4, row) * 8];
            f32x4 z = {0.f, 0.f, 0.f, 0.f};
            z = __builtin_amdgcn_mfma_f32_16x16x32_bf16(qa0, kb0, z, 0, 0, 0);
            z = __builtin_amdgcn_mfma_f32_16x16x32_bf16(qa1, kb1, z, 0, 0, 0);
            sj[j] = z;
        }
        __builtin_amdgcn_s_setprio(0);

        float lgv[4];
        #pragma unroll
        for (int j = 0; j < 4; ++j) lgv[j] = lg[k0 + j * 16 + mrow];
        #pragma unroll
        for (int j = 0; j < 4; ++j) {
            #pragma unroll
            for (int r = 0; r < 4; ++r) {
                float p = fexp2(fmaf(sj[j][r], C2, lgv[j])) * invl[r];
                int qr = q0 + wv * 16 + quad * 4 + r;
                wout[((size_t)bh * NQ + qr) * NK + k0 + j * 16 + mrow] = p;
                Ps[(wv * 16 + quad * 4 + r) * 72 + j * 16 + mrow] = (short)f2bf(p);
            }
        }

        __builtin_amdgcn_s_setprio(1);
        #pragma unroll
        for (int ks = 0; ks < 2; ++ks) {
            bf16x8 pa = *(const bf16x8*)&Ps[(wv * 16 + mrow) * 72 + ks * 32 + quad * 8];
            #pragma unroll
            for (int jp = 0; jp < 4; ++jp) {
                bf16x8 vb = *(const bf16x8*)&VTs[cur][(jp * 16 + mrow) * 72 + ks * 32 + quad * 8];
                o[jp] = __builtin_amdgcn_mfma_f32_16x16x32_bf16(pa, vb, o[jp], 0, 0, 0);
            }
        }
        __builtin_amdgcn_s_setprio(0);

        if (kt < 15) {
            // pack V(kt+1) (regs loaded last iter) into VTs[cur^1]; issue V(kt+2)
            #pragma unroll
            for (int jj = 0; jj < 8; ++jj) {
                short2v pr; pr[0] = v0r[jj]; pr[1] = v1r[jj];
                *(short2v*)&VTs[cur ^ 1][(dblk * 8 + jj) * 72 + 2 * kp] = pr;
            }
            if (kt < 14) {
                const short* p = Vb + (size_t)(b * NK + (kt + 2) * 64 + 2 * kp) * DD + h * DH + dblk * 8;
                v0r = *(const bf16x8*)p;
                v1r = *(const bf16x8*)(p + DD);
            }
        }
        __syncthreads();
    }

    #pragma unroll
    for (int jp = 0; jp < 4; ++jp)
        #pragma unroll
        for (int r = 0; r < 4; ++r)
            ctx[(size_t)(b * NQ + q0 + wv * 16 + quad * 4 + r) * DD + h * DH + jp * 16 + mrow] =
                (short)f2bf(o[jp][r]);
}

// ---- Residual + LayerNorm ----
__global__ __launch_bounds__(256) void add_ln(const float* __restrict__ X,
                                              const float* __restrict__ qx,
                                              const float* __restrict__ g,
                                              const float* __restrict__ bb,
                                              float* __restrict__ out)
{
    __shared__ float red[16];
    const int row = blockIdx.x;
    const int t = threadIdx.x;
    const float* xr = X + (size_t)row * DD;
    const float* qr = qx + (size_t)row * DD;
    float v0 = xr[t] + qr[t];
    float v1 = xr[t + 256] + qr[t + 256];
    float sum = v0 + v1;
    float sq = v0 * v0 + v1 * v1;
    #pragma unroll
    for (int off = 32; off > 0; off >>= 1) {
        sum += __shfl_down(sum, off);
        sq += __shfl_down(sq, off);
    }
    const int wid = t >> 6, lane = t & 63;
    if (lane == 0) { red[wid] = sum; red[8 + wid] = sq; }
    __syncthreads();
    if (t == 0) {
        float s = red[0] + red[1] + red[2] + red[3];
        float q2 = red[8] + red[9] + red[10] + red[11];
        float mu = s / (float)DD;
        float var = q2 / (float)DD - mu * mu;
        red[4] = mu;
        red[5] = rsqrtf(var + EPS);
    }
    __syncthreads();
    const float mu = red[4], inv = red[5];
    out[(size_t)row * DD + t] = (v0 - mu) * inv * g[t] + bb[t];
    out[(size_t)row * DD + t + 256] = (v1 - mu) * inv * g[t + 256] + bb[t + 256];
}

extern "C" void kernel_launch(void* const* d_in, const int* in_sizes, int n_in,
                              void* d_out, int out_size, void* d_ws, size_t ws_size,
                              hipStream_t stream) {
    const float* qx   = (const float*)d_in[0];
    const float* kx   = (const float*)d_in[1];
    const float* logg = (const float*)d_in[4];
    const float* Wq   = (const float*)d_in[5];
    const float* bq   = (const float*)d_in[6];
    const float* Wk   = (const float*)d_in[7];
    const float* bk   = (const float*)d_in[8];
    const float* Wv   = (const float*)d_in[9];
    const float* bv   = (const float*)d_in[10];
    const float* Wo   = (const float*)d_in[11];
    const float* bo   = (const float*)d_in[12];
    const float* ln_g = (const float*)d_in[13];
    const float* ln_b = (const float*)d_in[14];

    float* out0  = (float*)d_out;
    float* w_out = out0 + (size_t)BB * NQ * DD;

    const size_t rows = (size_t)BB * NQ;          // 4096
    short* WT  = (short*)d_ws;                    // 4 x 512 x 512 bf16 (2 MB)
    short* qxb = WT + (size_t)4 * DD * DD;
    short* kxb = qxb + rows * DD;
    short* Qb  = kxb + rows * DD;
    short* Kb  = Qb + rows * DD;
    short* Vb  = Kb + rows * DD;
    short* Cxb = Vb + rows * DD;
    float* Xb  = (float*)(Cxb + rows * DD);

    wconv<<<dim3(DD / 32, DD / 32, 4), 256, 0, stream>>>(Wq, Wk, Wv, Wo, WT);
    cvt_bf16<<<2048, 256, 0, stream>>>(qx, kx, qxb, kxb);

    gemm128<0><<<dim3(1536 / 64, (int)(rows / 128)), 256, 0, stream>>>(
        qxb, kxb, WT, bq, bk, bv, Qb, Kb, Vb);

    attn_fused<<<dim3(512), 256, 0, stream>>>(Qb, Kb, Vb, logg, w_out, Cxb);

    gemm128<1><<<dim3(DD / 64, (int)(rows / 128)), 256, 0, stream>>>(
        Cxb, nullptr, WT + 3 * DD * DD, bo, nullptr, nullptr, Xb, nullptr, nullptr);

    add_ln<<<(int)rows, 256, 0, stream>>>(Xb, qx, ln_g, ln_b, out0);
}